// Round 4
// baseline (441.515 us; speedup 1.0000x reference)
//
#include <hip/hip_runtime.h>
#include <hip/hip_bf16.h>
#include <hip/hip_cooperative_groups.h>

namespace cg = cooperative_groups;

// Problem constants (from reference)
#define BATCH 16384
#define HD    1024
#define NP    48
#define PPC   24
#define EPSV  1e-4f

typedef __attribute__((ext_vector_type(8))) short  short8;
typedef __attribute__((ext_vector_type(4))) float  floatx4;

__device__ __forceinline__ float b2f(unsigned short s) {
    union { unsigned u; float f; } c; c.u = ((unsigned)s) << 16; return c.f;
}
__device__ __forceinline__ unsigned short f2bu(float f) {
    __hip_bfloat16 h = __float2bfloat16(f);  // RNE
    union { __hip_bfloat16 h; unsigned short u; } c; c.h = h; return c.u;
}

// ===================================================================
// FUSED single-dispatch pipeline (cooperative launch, grid.sync between
// phases). Round-3 post-mortem: sum of kernel dur ~108us vs dur_us 236 ->
// ~20-25us per dispatch boundary dominates. One kernel removes 4 boundaries.
// All phase bodies are arithmetic-identical to the verified round-3 kernels.
// Grid is set from an occupancy query (min(2048, blocksPerCU*256)); every
// phase is grid-strided so ANY granted grid size is correct.
// ===================================================================
__global__ __launch_bounds__(256, 4) void k_fused(
    const float* __restrict__ x,
    const float* __restrict__ sh,
    const float* __restrict__ proto,
    const float* __restrict__ llw,
    const float* __restrict__ w2,
    const float* __restrict__ bb,
    const int*   __restrict__ flag,
    float* __restrict__ out_pos,
    float* __restrict__ out_copy,
    float* __restrict__ out_logits,
    float* __restrict__ out_dist,
    unsigned short* __restrict__ phi,
    unsigned short* __restrict__ plo,
    float* __restrict__ p2,
    float* __restrict__ v,
    float* __restrict__ gcol,
    float* __restrict__ dotp,
    float* __restrict__ x2h)
{
    __shared__ float lacc[4][64][13];   // 13: pad; gcd(13,32)=1 -> conflict-free
    __shared__ float lx2[4][16];
    __shared__ float gsum[NP];
    __shared__ float wsum[4];
    __shared__ int   js;

    cg::grid_group grid = cg::this_grid();
    const int bid  = blockIdx.x;
    const int G    = gridDim.x;
    const int tid  = threadIdx.x;
    const int wave = tid >> 6;
    const int lane = tid & 63;
    const int quad = lane >> 4;
    const int lr   = lane & 15;

    // ---------------- Phase 0: proto -> (hi,lo) bf16 split + p2; zero v/gcol
    for (int p = bid; p < 48; p += G) {
        if (p < 4)                   v[p * 256 + tid] = 0.f;
        else if (p == 4 && tid < NP) gcol[tid] = 0.f;
        const float* row = proto + (size_t)p * HD;
        float acc = 0.f;
#pragma unroll
        for (int c = 0; c < 4; ++c) {
            const int k = c * 256 + tid;
            const float f = row[k];
            acc += f * f;
            const unsigned short h = f2bu(f);
            phi[(size_t)p * HD + k] = h;
            plo[(size_t)p * HD + k] = f2bu(f - b2f(h));
        }
#pragma unroll
        for (int m = 32; m >= 1; m >>= 1) acc += __shfl_xor(acc, m, 64);
        if (lane == 0) wsum[wave] = acc;
        __syncthreads();
        if (tid == 0) p2[p] = wsum[0] + wsum[1] + wsum[2] + wsum[3];
        __syncthreads();
    }
    grid.sync();

    // ---------------- Phase 1: K-split GEMM (band*2+kh blocks of work)
    // Identical math to round-3 k_mainA: 16-row band x 48 protos x K-half;
    // wave = K-eighth. 52-VGPR loop; <=64 VGPR keeps 8 waves/SIMD.
    for (int vb = bid; vb < 2048; vb += G) {
        const int band = vb >> 1;
        const int kh   = vb & 1;
        const int rb   = band * 16;
        const int ko   = kh * 512 + wave * 128;

        const float* xr = x + (size_t)(rb + lr) * HD + ko + quad * 8;
        const unsigned short* ph0 = phi + (size_t)lr * HD + ko + quad * 8;
        const unsigned short* ph1 = ph0 + 16 * HD;
        const unsigned short* ph2 = ph0 + 32 * HD;
        const unsigned short* pl0 = plo + (size_t)lr * HD + ko + quad * 8;
        const unsigned short* pl1 = pl0 + 16 * HD;
        const unsigned short* pl2 = pl0 + 32 * HD;

        floatx4 acc0 = {0.f, 0.f, 0.f, 0.f};
        floatx4 acc1 = {0.f, 0.f, 0.f, 0.f};
        floatx4 acc2 = {0.f, 0.f, 0.f, 0.f};
        float x2p = 0.f;

#pragma unroll 2
        for (int kk = 0; kk < 4; ++kk) {
            const floatx4 xa = *(const floatx4*)(xr + kk * 32);
            const floatx4 xb = *(const floatx4*)(xr + kk * 32 + 4);
            short8 ah, al;
#pragma unroll
            for (int j = 0; j < 4; ++j) {
                const float f = xa[j];
                x2p += f * f;
                const unsigned short h = f2bu(f);
                ah[j] = (short)h;
                al[j] = (short)f2bu(f - b2f(h));
            }
#pragma unroll
            for (int j = 0; j < 4; ++j) {
                const float f = xb[j];
                x2p += f * f;
                const unsigned short h = f2bu(f);
                ah[4 + j] = (short)h;
                al[4 + j] = (short)f2bu(f - b2f(h));
            }
            const short8 bh0 = *(const short8*)(ph0 + kk * 32);
            const short8 bh1 = *(const short8*)(ph1 + kk * 32);
            const short8 bh2 = *(const short8*)(ph2 + kk * 32);
            const short8 bl0 = *(const short8*)(pl0 + kk * 32);
            const short8 bl1 = *(const short8*)(pl1 + kk * 32);
            const short8 bl2 = *(const short8*)(pl2 + kk * 32);
            acc0 = __builtin_amdgcn_mfma_f32_16x16x32_bf16(ah, bh0, acc0, 0, 0, 0);
            acc0 = __builtin_amdgcn_mfma_f32_16x16x32_bf16(ah, bl0, acc0, 0, 0, 0);
            acc0 = __builtin_amdgcn_mfma_f32_16x16x32_bf16(al, bh0, acc0, 0, 0, 0);
            acc1 = __builtin_amdgcn_mfma_f32_16x16x32_bf16(ah, bh1, acc1, 0, 0, 0);
            acc1 = __builtin_amdgcn_mfma_f32_16x16x32_bf16(ah, bl1, acc1, 0, 0, 0);
            acc1 = __builtin_amdgcn_mfma_f32_16x16x32_bf16(al, bh1, acc1, 0, 0, 0);
            acc2 = __builtin_amdgcn_mfma_f32_16x16x32_bf16(ah, bh2, acc2, 0, 0, 0);
            acc2 = __builtin_amdgcn_mfma_f32_16x16x32_bf16(ah, bl2, acc2, 0, 0, 0);
            acc2 = __builtin_amdgcn_mfma_f32_16x16x32_bf16(al, bh2, acc2, 0, 0, 0);
        }
        x2p += __shfl_xor(x2p, 16, 64);
        x2p += __shfl_xor(x2p, 32, 64);

#pragma unroll
        for (int r = 0; r < 4; ++r) {
            lacc[wave][lane][r]     = acc0[r];
            lacc[wave][lane][4 + r] = acc1[r];
            lacc[wave][lane][8 + r] = acc2[r];
        }
        if (quad == 0) lx2[wave][lr] = x2p;
        __syncthreads();
        if (wave == 0) {
            float facc[12];
#pragma unroll
            for (int i = 0; i < 12; ++i)
                facc[i] = lacc[0][lane][i] + lacc[1][lane][i] + lacc[2][lane][i] + lacc[3][lane][i];
            const float x2full = lx2[0][lr] + lx2[1][lr] + lx2[2][lr] + lx2[3][lr];

            float* drow = dotp + ((size_t)kh * 1024 + band) * (16 * NP);
#pragma unroll
            for (int t = 0; t < 3; ++t)
#pragma unroll
                for (int r = 0; r < 4; ++r)
                    drow[(quad * 4 + r) * NP + t * 16 + lr] = facc[t * 4 + r];
            if (quad == 0) x2h[((size_t)kh * 1024 + band) * 16 + lr] = x2full;
        }
        __syncthreads();   // protect lacc/lx2 for next grid-stride iteration
    }
    grid.sync();

    // ---------------- Phase 2: combine K-halves, dist/sim/logits/gcol
    for (int band = bid; band < 1024; band += G) {
        if (tid < NP) gsum[tid] = 0.f;
        __syncthreads();

        const float p2p = (lane < NP) ? p2[lane] : 0.f;
        const float w0  = (lane < NP) ? llw[lane] : 0.f;
        const float w1  = (lane < NP) ? llw[NP + lane] : 0.f;
        const float* dA = dotp + (size_t)band * (16 * NP);
        const float* dB = dotp + ((size_t)1024 + band) * (16 * NP);
        float csum = 0.f;

#pragma unroll
        for (int r = 0; r < 4; ++r) {
            const int rrow = wave * 4 + r;
            const int row  = band * 16 + rrow;
            const float x2 = x2h[band * 16 + rrow] + x2h[1024 * 16 + band * 16 + rrow];
            float sim = 0.f;
            if (lane < NP) {
                const float dot = dA[rrow * NP + lane] + dB[rrow * NP + lane];
                const float d = -2.f * dot + x2 + p2p;
                out_dist[(size_t)row * NP + lane] = d;
                sim = log1pf((1.f - EPSV) / (d + EPSV));
            }
            csum += sim;
            float r0 = sim * w0, r1 = sim * w1;
#pragma unroll
            for (int m = 1; m <= 32; m <<= 1) {
                r0 += __shfl_xor(r0, m, 64);
                r1 += __shfl_xor(r1, m, 64);
            }
            if (lane == 0) {
                out_logits[(size_t)row * 2 + 0] = r0;
                out_logits[(size_t)row * 2 + 1] = r1;
            }
        }
        if (lane < NP) atomicAdd(&gsum[lane], csum);
        __syncthreads();
        if (tid < NP) atomicAdd(&gcol[tid], gsum[tid]);
        __syncthreads();   // protect gsum for next grid-stride iteration
    }
    grid.sync();

    // ---------------- Phase 3: argmax over gcol, v = chosen^T W2
    {
        const int idx = (flag[0] != 0) ? 1 : 0;
        for (int vb = bid; vb < 256; vb += G) {
            if (tid == 0) {
                const float* cs = gcol + idx * PPC;
                int bj = 0; float bv = cs[0];
                for (int j = 1; j < PPC; ++j)
                    if (cs[j] > bv) { bv = cs[j]; bj = j; }   // first-max
                js = bj;
            }
            __syncthreads();
            const float* crow = proto + (size_t)(idx * PPC + js) * HD;
            const int i0 = vb * 4;
            const int j4 = tid * 4;
            float a0 = 0.f, a1 = 0.f, a2 = 0.f, a3 = 0.f;
#pragma unroll
            for (int i = i0; i < i0 + 4; ++i) {
                const float c = crow[i];
                const floatx4 wv = *(const floatx4*)(w2 + (size_t)i * HD + j4);
                a0 += c * wv[0];
                a1 += c * wv[1];
                a2 += c * wv[2];
                a3 += c * wv[3];
            }
            atomicAdd(&v[j4 + 0], a0);
            atomicAdd(&v[j4 + 1], a1);
            atomicAdd(&v[j4 + 2], a2);
            atomicAdd(&v[j4 + 3], a3);
            __syncthreads();   // protect js for next grid-stride iteration
        }
    }
    grid.sync();

    // ---------------- Phase 4: pos[b] = v . shared[b] + bias; streaming copy
    for (int vb = bid; vb < 4096; vb += G) {
        const int b = vb * 4 + wave;
        const floatx4* src = (const floatx4*)(sh + (size_t)b * HD);
        floatx4* dst = (floatx4*)(out_copy + (size_t)b * HD);
        const floatx4* vv = (const floatx4*)v;
        float acc = 0.f;
#pragma unroll
        for (int c = 0; c < 4; ++c) {
            const int idx2 = c * 64 + lane;
            const floatx4 r = src[idx2];
            __builtin_nontemporal_store(r, &dst[idx2]);   // bit-exact copy
            const floatx4 vr = vv[idx2];
#pragma unroll
            for (int j = 0; j < 4; ++j) acc += r[j] * vr[j];
        }
#pragma unroll
        for (int m = 1; m <= 32; m <<= 1) acc += __shfl_xor(acc, m, 64);
        if (lane == 0) out_pos[b] = acc + bb[0];
    }
}

// ===================================================================
// Fallback multi-kernel path (verified round-3 pipeline) — used only if the
// cooperative launch is unavailable or ws too small.
// ===================================================================
__global__ __launch_bounds__(256) void k_prep(const float* __restrict__ proto,
                                              unsigned short* __restrict__ phi,
                                              unsigned short* __restrict__ plo,
                                              float* __restrict__ p2,
                                              float* __restrict__ vzero,
                                              float* __restrict__ gcol) {
    const int p = blockIdx.x;
    const int tid = threadIdx.x;
    if (p < 4)                        vzero[p * 256 + tid] = 0.f;
    else if (p == 4 && tid < NP)      gcol[tid] = 0.f;

    const float* row = proto + (size_t)p * HD;
    float acc = 0.f;
#pragma unroll
    for (int c = 0; c < 4; ++c) {
        const int k = c * 256 + tid;
        const float f = row[k];
        acc += f * f;
        const unsigned short h = f2bu(f);
        phi[(size_t)p * HD + k] = h;
        plo[(size_t)p * HD + k] = f2bu(f - b2f(h));
    }
#pragma unroll
    for (int m = 32; m >= 1; m >>= 1) acc += __shfl_xor(acc, m, 64);
    __shared__ float wsum[4];
    if ((tid & 63) == 0) wsum[tid >> 6] = acc;
    __syncthreads();
    if (tid == 0) p2[p] = wsum[0] + wsum[1] + wsum[2] + wsum[3];
}

__global__ __launch_bounds__(256, 4) void k_main_fb(
    const float* __restrict__ x,
    const unsigned short* __restrict__ phi,
    const unsigned short* __restrict__ plo,
    const float* __restrict__ llw,
    const float* __restrict__ p2,
    float* __restrict__ gcol,
    float* __restrict__ out_logits,
    float* __restrict__ out_dist)
{
    __shared__ float lacc[4][64][13];
    __shared__ float lx2[4][16];
    const int wave = threadIdx.x >> 6;
    const int lane = threadIdx.x & 63;
    const int quad = lane >> 4;
    const int lr   = lane & 15;
    const int rb   = blockIdx.x * 16;
    const int ko   = wave * 256;

    const float* xr = x + (size_t)(rb + lr) * HD + ko + quad * 8;
    const unsigned short* ph0 = phi + (size_t)lr * HD + ko + quad * 8;
    const unsigned short* ph1 = ph0 + 16 * HD;
    const unsigned short* ph2 = ph0 + 32 * HD;
    const unsigned short* pl0 = plo + (size_t)lr * HD + ko + quad * 8;
    const unsigned short* pl1 = pl0 + 16 * HD;
    const unsigned short* pl2 = pl0 + 32 * HD;

    floatx4 acc0 = {0.f, 0.f, 0.f, 0.f};
    floatx4 acc1 = {0.f, 0.f, 0.f, 0.f};
    floatx4 acc2 = {0.f, 0.f, 0.f, 0.f};
    float x2p = 0.f;

#pragma unroll 2
    for (int kk = 0; kk < 8; ++kk) {
        const floatx4 xa = *(const floatx4*)(xr + kk * 32);
        const floatx4 xb = *(const floatx4*)(xr + kk * 32 + 4);
        short8 ah, al;
#pragma unroll
        for (int j = 0; j < 4; ++j) {
            const float f = xa[j];
            x2p += f * f;
            const unsigned short h = f2bu(f);
            ah[j] = (short)h;
            al[j] = (short)f2bu(f - b2f(h));
        }
#pragma unroll
        for (int j = 0; j < 4; ++j) {
            const float f = xb[j];
            x2p += f * f;
            const unsigned short h = f2bu(f);
            ah[4 + j] = (short)h;
            al[4 + j] = (short)f2bu(f - b2f(h));
        }
        const short8 bh0 = *(const short8*)(ph0 + kk * 32);
        const short8 bh1 = *(const short8*)(ph1 + kk * 32);
        const short8 bh2 = *(const short8*)(ph2 + kk * 32);
        const short8 bl0 = *(const short8*)(pl0 + kk * 32);
        const short8 bl1 = *(const short8*)(pl1 + kk * 32);
        const short8 bl2 = *(const short8*)(pl2 + kk * 32);
        acc0 = __builtin_amdgcn_mfma_f32_16x16x32_bf16(ah, bh0, acc0, 0, 0, 0);
        acc0 = __builtin_amdgcn_mfma_f32_16x16x32_bf16(ah, bl0, acc0, 0, 0, 0);
        acc0 = __builtin_amdgcn_mfma_f32_16x16x32_bf16(al, bh0, acc0, 0, 0, 0);
        acc1 = __builtin_amdgcn_mfma_f32_16x16x32_bf16(ah, bh1, acc1, 0, 0, 0);
        acc1 = __builtin_amdgcn_mfma_f32_16x16x32_bf16(ah, bl1, acc1, 0, 0, 0);
        acc1 = __builtin_amdgcn_mfma_f32_16x16x32_bf16(al, bh1, acc1, 0, 0, 0);
        acc2 = __builtin_amdgcn_mfma_f32_16x16x32_bf16(ah, bh2, acc2, 0, 0, 0);
        acc2 = __builtin_amdgcn_mfma_f32_16x16x32_bf16(ah, bl2, acc2, 0, 0, 0);
        acc2 = __builtin_amdgcn_mfma_f32_16x16x32_bf16(al, bh2, acc2, 0, 0, 0);
    }
    x2p += __shfl_xor(x2p, 16, 64);
    x2p += __shfl_xor(x2p, 32, 64);

#pragma unroll
    for (int r = 0; r < 4; ++r) {
        lacc[wave][lane][r]     = acc0[r];
        lacc[wave][lane][4 + r] = acc1[r];
        lacc[wave][lane][8 + r] = acc2[r];
    }
    if (quad == 0) lx2[wave][lr] = x2p;
    __syncthreads();
    if (wave != 0) return;

    float facc[12];
#pragma unroll
    for (int i = 0; i < 12; ++i)
        facc[i] = lacc[0][lane][i] + lacc[1][lane][i] + lacc[2][lane][i] + lacc[3][lane][i];
    const float x2full = lx2[0][lr] + lx2[1][lr] + lx2[2][lr] + lx2[3][lr];

    float s0[4] = {0.f, 0.f, 0.f, 0.f};
    float s1[4] = {0.f, 0.f, 0.f, 0.f};

#pragma unroll
    for (int t = 0; t < 3; ++t) {
        const int p = t * 16 + lr;
        const float p2p = p2[p];
        const float w0 = llw[p];
        const float w1 = llw[NP + p];
        float cst = 0.f;
#pragma unroll
        for (int r = 0; r < 4; ++r) {
            const int row = quad * 4 + r;
            const float x2r = __shfl(x2full, row, 64);
            const float d = -2.f * facc[t * 4 + r] + x2r + p2p;
            out_dist[(size_t)(rb + row) * NP + p] = d;
            const float sim = log1pf((1.f - EPSV) / (d + EPSV));
            s0[r] += sim * w0;
            s1[r] += sim * w1;
            cst += sim;
        }
        cst += __shfl_xor(cst, 16, 64);
        cst += __shfl_xor(cst, 32, 64);
        if (quad == 0) atomicAdd(&gcol[p], cst);
    }

#pragma unroll
    for (int r = 0; r < 4; ++r) {
        float r0 = s0[r], r1 = s1[r];
#pragma unroll
        for (int m = 1; m <= 8; m <<= 1) {
            r0 += __shfl_xor(r0, m, 64);
            r1 += __shfl_xor(r1, m, 64);
        }
        if (lr == 0) {
            const int brow = rb + quad * 4 + r;
            out_logits[(size_t)brow * 2 + 0] = r0;
            out_logits[(size_t)brow * 2 + 1] = r1;
        }
    }
}

__global__ __launch_bounds__(256) void k_matvec(
    const float* __restrict__ proto,
    const float* __restrict__ w2,
    const float* __restrict__ gcol,
    const int* __restrict__ flag,
    float* __restrict__ v)
{
    __shared__ int js;
    const int tid = threadIdx.x;
    const int idx = (flag[0] != 0) ? 1 : 0;
    if (tid == 0) {
        const float* cs = gcol + idx * PPC;
        int bj = 0; float bv = cs[0];
        for (int j = 1; j < PPC; ++j)
            if (cs[j] > bv) { bv = cs[j]; bj = j; }
        js = bj;
    }
    __syncthreads();

    const float* crow = proto + (size_t)(idx * PPC + js) * HD;
    const int i0 = blockIdx.x * 16;
    const int j4 = tid * 4;
    float a0 = 0.f, a1 = 0.f, a2 = 0.f, a3 = 0.f;
#pragma unroll 4
    for (int i = i0; i < i0 + 16; ++i) {
        const float c = crow[i];
        const floatx4 wv = *(const floatx4*)(w2 + (size_t)i * HD + j4);
        a0 += c * wv[0];
        a1 += c * wv[1];
        a2 += c * wv[2];
        a3 += c * wv[3];
    }
    atomicAdd(&v[j4 + 0], a0);
    atomicAdd(&v[j4 + 1], a1);
    atomicAdd(&v[j4 + 2], a2);
    atomicAdd(&v[j4 + 3], a3);
}

__global__ __launch_bounds__(256) void k_pos(
    const float* __restrict__ sh,
    const float* __restrict__ v,
    const float* __restrict__ bias,
    float* __restrict__ out_pos,
    float* __restrict__ out_copy)
{
    const int wave = threadIdx.x >> 6;
    const int lane = threadIdx.x & 63;
    const int b = blockIdx.x * 4 + wave;

    const floatx4* src = (const floatx4*)(sh + (size_t)b * HD);
    floatx4* dst = (floatx4*)(out_copy + (size_t)b * HD);
    const floatx4* vv = (const floatx4*)v;
    float acc = 0.f;
#pragma unroll
    for (int c = 0; c < 4; ++c) {
        const int idx = c * 64 + lane;
        const floatx4 r = src[idx];
        __builtin_nontemporal_store(r, &dst[idx]);
        const floatx4 vr = vv[idx];
#pragma unroll
        for (int j = 0; j < 4; ++j) acc += r[j] * vr[j];
    }
#pragma unroll
    for (int m = 1; m <= 32; m <<= 1) acc += __shfl_xor(acc, m, 64);
    if (lane == 0) out_pos[b] = acc + bias[0];
}

extern "C" void kernel_launch(void* const* d_in, const int* in_sizes, int n_in,
                              void* d_out, int out_size, void* d_ws, size_t ws_size,
                              hipStream_t stream) {
    const float* x     = (const float*)d_in[0];  // specific_user [B,H] fp32
    const float* sh    = (const float*)d_in[1];  // shared_user   [B,H] fp32
    const float* proto = (const float*)d_in[2];  // [48,H] fp32
    const float* llw   = (const float*)d_in[3];  // [2,48] fp32
    const float* w2    = (const float*)d_in[4];  // [1,H,H] fp32
    const float* bb    = (const float*)d_in[5];  // [1] fp32
    const int*   flag  = (const int*)d_in[6];    // [1] int32

    float* out = (float*)d_out;
    // outputs flat: pos [B,1] | shared copy [B,H] | logits [B,2] | distance [B,48]
    float* out_pos    = out;
    float* out_copy   = out + BATCH;
    float* out_logits = out + BATCH + BATCH * HD;
    float* out_dist   = out + BATCH + BATCH * HD + BATCH * 2;

    // workspace layout (floats):
    //   [0,1024) v | [1024,1072) gcol | [1088,1136) p2
    //   [16384,40960) phi | [40960,65536) plo
    //   [65536,1638400) dotp [2][1024][768] | [1638400,1671168) x2h
    float* ws_v    = (float*)d_ws;
    float* ws_col  = ws_v + 1024;
    float* ws_p2   = ws_v + 1088;
    unsigned short* ws_phi = (unsigned short*)(ws_v + 16384);
    unsigned short* ws_plo = ws_phi + NP * HD;
    float* ws_dot  = ws_v + 65536;
    float* ws_x2   = ws_v + 1638400;
    const bool big_ws = ws_size >= (size_t)1671168 * 4;

    bool launched = false;
    if (big_ws) {
        // Cooperative grid: min(2048, blocks/CU * 256 CUs); phases grid-stride
        // so any granted size is correct. Cached across calls.
        static int coop_grid = 0;
        if (coop_grid == 0) {
            int nb = 0;
            if (hipOccupancyMaxActiveBlocksPerMultiprocessor(&nb, k_fused, 256, 0) != hipSuccess || nb < 1)
                nb = 0;
            long g = (long)nb * 256;          // 256 CUs on MI355X
            if (g > 2048) g = 2048;
            coop_grid = (int)g;               // 0 -> cooperative path disabled
        }
        if (coop_grid >= 256) {
            void* args[] = {
                (void*)&x, (void*)&sh, (void*)&proto, (void*)&llw, (void*)&w2,
                (void*)&bb, (void*)&flag, (void*)&out_pos, (void*)&out_copy,
                (void*)&out_logits, (void*)&out_dist, (void*)&ws_phi,
                (void*)&ws_plo, (void*)&ws_p2, (void*)&ws_v, (void*)&ws_col,
                (void*)&ws_dot, (void*)&ws_x2 };
            hipError_t e = hipLaunchCooperativeKernel(
                (void*)k_fused, dim3(coop_grid), dim3(256), args, 0, stream);
            launched = (e == hipSuccess);
        }
    }

    if (!launched) {
        // verified multi-kernel fallback (round-3 behavior, single-pass GEMM)
        k_prep<<<48, 256, 0, stream>>>(proto, ws_phi, ws_plo, ws_p2, ws_v, ws_col);
        k_main_fb<<<1024, 256, 0, stream>>>(x, ws_phi, ws_plo, llw, ws_p2, ws_col, out_logits, out_dist);
        k_matvec<<<64, 256, 0, stream>>>(proto, w2, ws_col, flag, ws_v);
        k_pos<<<4096, 256, 0, stream>>>(sh, ws_v, bb, out_pos, out_copy);
    }
}

// Round 5
// 282.608 us; speedup vs baseline: 1.5623x; 1.5623x over previous
//
#include <hip/hip_runtime.h>
#include <hip/hip_bf16.h>

// Problem constants (from reference)
#define BATCH 16384
#define HD    1024
#define NP    48
#define PPC   24
#define EPSV  1e-4f

typedef __attribute__((ext_vector_type(8))) short  short8;
typedef __attribute__((ext_vector_type(4))) float  floatx4;

__device__ __forceinline__ float b2f(unsigned short s) {
    union { unsigned u; float f; } c; c.u = ((unsigned)s) << 16; return c.f;
}
__device__ __forceinline__ unsigned short f2bu(float f) {
    __hip_bfloat16 h = __float2bfloat16(f);  // RNE
    union { __hip_bfloat16 h; unsigned short u; } c; c.h = h; return c.u;
}

// ---------------------------------------------------------------------------
// Round-5 structure: 3 dispatches (boundaries cost ~21 us each; round-4
// proved grid.sync costs ~90 us, so fewer STAGES not fused kernels):
//   k_prep : blocks 0-47  -> proto (hi,lo) bf16 split + p2 (+ zero gcol)
//            blocks 48-143-> V[j][c] = proto[class,j] . W2[:,c] for ALL 24
//                            candidate prototypes (jstar-independent!)
//   k_main : verified round-0 GEMM + epilogue (52 VGPR, no spill)
//   k_pos  : computes jstar per-block from gcol (48 floats, L2-broadcast),
//            then pos[b] = V[jstar] . sh[b] + bias; streaming copy of sh.
// This removes the k_matvec stage + old memset dispatch entirely.
// ---------------------------------------------------------------------------
__global__ __launch_bounds__(256) void k_prep(const float* __restrict__ proto,
                                              const float* __restrict__ w2,
                                              const int*   __restrict__ flag,
                                              unsigned short* __restrict__ phi,
                                              unsigned short* __restrict__ plo,
                                              float* __restrict__ p2,
                                              float* __restrict__ gcol,   // [48]
                                              float* __restrict__ V) {    // [24][1024]
    const int bid = blockIdx.x;
    const int tid = threadIdx.x;

    if (bid < 48) {
        // ---- proto -> (hi,lo) bf16 split + p2; block 4 zeroes gcol
        const int p = bid;
        if (p == 4 && tid < NP) gcol[tid] = 0.f;
        const float* row = proto + (size_t)p * HD;
        float acc = 0.f;
#pragma unroll
        for (int c = 0; c < 4; ++c) {
            const int k = c * 256 + tid;
            const float f = row[k];
            acc += f * f;
            const unsigned short h = f2bu(f);
            phi[(size_t)p * HD + k] = h;
            plo[(size_t)p * HD + k] = f2bu(f - b2f(h));
        }
#pragma unroll
        for (int m = 32; m >= 1; m >>= 1) acc += __shfl_xor(acc, m, 64);
        __shared__ float wsum[4];
        if ((tid & 63) == 0) wsum[tid >> 6] = acc;
        __syncthreads();
        if (tid == 0) p2[p] = wsum[0] + wsum[1] + wsum[2] + wsum[3];
    } else {
        // ---- candidate matvec: V[j][c] = sum_i proto[idx*24+j][i] * W2[i][c]
        // 96 blocks: q = jg*16 + cc; wave = one of 4 j's, lane = one of 64 c's.
        // proto load is wave-uniform (HW broadcast); W2 load is 64x4B coalesced.
        const int q   = bid - 48;            // [0,96)
        const int jg  = q >> 4;              // 0..5  (groups of 4 prototypes)
        const int cc  = q & 15;              // 0..15 (64-column chunks)
        const int c   = cc * 64 + (tid & 63);
        const int j   = jg * 4 + (tid >> 6);
        const int idx = (flag[0] != 0) ? 1 : 0;
        const float* prow = proto + (size_t)(idx * PPC + j) * HD;
        float acc = 0.f;
#pragma unroll 2
        for (int i = 0; i < HD; i += 4) {
            const floatx4 pv = *(const floatx4*)(prow + i);
            acc += pv[0] * w2[(size_t)(i + 0) * HD + c];
            acc += pv[1] * w2[(size_t)(i + 1) * HD + c];
            acc += pv[2] * w2[(size_t)(i + 2) * HD + c];
            acc += pv[3] * w2[(size_t)(i + 3) * HD + c];
        }
        V[(size_t)j * HD + c] = acc;
    }
}

// ------------------------------------------------- main GEMM + epilogue
// VERIFIED round-0 kernel, unchanged. grid 1024 x block 256 (4 waves).
// Block owns one 16-row band x all 48 protos; each wave a K-quarter (256).
// __launch_bounds__(256,4): 128-VGPR budget -> compiles to 52 VGPR, no spill
// (rounds 1/2 proved any cap at 64 spills ~40MB scratch). fp32 via
// split-bf16: x.p ~= xh.ph + xh.pl + xl.ph (3 MFMAs). MFMA 16x16x32 bf16:
// A[m=lane&15][k=quad*8+j], B[k=quad*8+j][n=lane&15], C/D col=lane&15,
// row=quad*4+reg.
__global__ __launch_bounds__(256, 4) void k_main(
    const float* __restrict__ x,
    const unsigned short* __restrict__ phi,
    const unsigned short* __restrict__ plo,
    const float* __restrict__ llw,       // [2,48] fp32
    const float* __restrict__ p2,
    float* __restrict__ gcol,            // [48] fp32, pre-zeroed (atomic)
    float* __restrict__ out_logits,      // [B,2]
    float* __restrict__ out_dist)        // [B,48]
{
    __shared__ float lacc[4][64][13];    // 13: pad (12-stride = 8-way conflict)
    __shared__ float lx2[4][16];
    const int wave = threadIdx.x >> 6;
    const int lane = threadIdx.x & 63;
    const int quad = lane >> 4;
    const int lr   = lane & 15;
    const int rb   = blockIdx.x * 16;
    const int ko   = wave * 256;         // this wave's K-quarter

    const float* xr = x + (size_t)(rb + lr) * HD + ko + quad * 8;
    const unsigned short* ph0 = phi + (size_t)lr * HD + ko + quad * 8;
    const unsigned short* ph1 = ph0 + 16 * HD;
    const unsigned short* ph2 = ph0 + 32 * HD;
    const unsigned short* pl0 = plo + (size_t)lr * HD + ko + quad * 8;
    const unsigned short* pl1 = pl0 + 16 * HD;
    const unsigned short* pl2 = pl0 + 32 * HD;

    floatx4 acc0 = {0.f, 0.f, 0.f, 0.f};
    floatx4 acc1 = {0.f, 0.f, 0.f, 0.f};
    floatx4 acc2 = {0.f, 0.f, 0.f, 0.f};
    float x2p = 0.f;

#pragma unroll 2
    for (int kk = 0; kk < 8; ++kk) {
        const floatx4 xa = *(const floatx4*)(xr + kk * 32);
        const floatx4 xb = *(const floatx4*)(xr + kk * 32 + 4);
        short8 ah, al;
#pragma unroll
        for (int j = 0; j < 4; ++j) {
            const float f = xa[j];
            x2p += f * f;
            const unsigned short h = f2bu(f);
            ah[j] = (short)h;
            al[j] = (short)f2bu(f - b2f(h));
        }
#pragma unroll
        for (int j = 0; j < 4; ++j) {
            const float f = xb[j];
            x2p += f * f;
            const unsigned short h = f2bu(f);
            ah[4 + j] = (short)h;
            al[4 + j] = (short)f2bu(f - b2f(h));
        }
        const short8 bh0 = *(const short8*)(ph0 + kk * 32);
        const short8 bh1 = *(const short8*)(ph1 + kk * 32);
        const short8 bh2 = *(const short8*)(ph2 + kk * 32);
        const short8 bl0 = *(const short8*)(pl0 + kk * 32);
        const short8 bl1 = *(const short8*)(pl1 + kk * 32);
        const short8 bl2 = *(const short8*)(pl2 + kk * 32);
        acc0 = __builtin_amdgcn_mfma_f32_16x16x32_bf16(ah, bh0, acc0, 0, 0, 0);
        acc0 = __builtin_amdgcn_mfma_f32_16x16x32_bf16(ah, bl0, acc0, 0, 0, 0);
        acc0 = __builtin_amdgcn_mfma_f32_16x16x32_bf16(al, bh0, acc0, 0, 0, 0);
        acc1 = __builtin_amdgcn_mfma_f32_16x16x32_bf16(ah, bh1, acc1, 0, 0, 0);
        acc1 = __builtin_amdgcn_mfma_f32_16x16x32_bf16(ah, bl1, acc1, 0, 0, 0);
        acc1 = __builtin_amdgcn_mfma_f32_16x16x32_bf16(al, bh1, acc1, 0, 0, 0);
        acc2 = __builtin_amdgcn_mfma_f32_16x16x32_bf16(ah, bh2, acc2, 0, 0, 0);
        acc2 = __builtin_amdgcn_mfma_f32_16x16x32_bf16(ah, bl2, acc2, 0, 0, 0);
        acc2 = __builtin_amdgcn_mfma_f32_16x16x32_bf16(al, bh2, acc2, 0, 0, 0);
    }
    // per-wave: x2 partial for row lr over this wave's K-quarter
    x2p += __shfl_xor(x2p, 16, 64);
    x2p += __shfl_xor(x2p, 32, 64);

    // stash partial accumulators, combine on wave 0
#pragma unroll
    for (int r = 0; r < 4; ++r) {
        lacc[wave][lane][r]     = acc0[r];
        lacc[wave][lane][4 + r] = acc1[r];
        lacc[wave][lane][8 + r] = acc2[r];
    }
    if (quad == 0) lx2[wave][lr] = x2p;
    __syncthreads();
    if (wave != 0) return;

    float facc[12];
#pragma unroll
    for (int i = 0; i < 12; ++i)
        facc[i] = lacc[0][lane][i] + lacc[1][lane][i] + lacc[2][lane][i] + lacc[3][lane][i];
    const float x2full = lx2[0][lr] + lx2[1][lr] + lx2[2][lr] + lx2[3][lr]; // row lr

    float s0[4] = {0.f, 0.f, 0.f, 0.f};
    float s1[4] = {0.f, 0.f, 0.f, 0.f};

#pragma unroll
    for (int t = 0; t < 3; ++t) {
        const int p = t * 16 + lr;
        const float p2p = p2[p];
        const float w0 = llw[p];
        const float w1 = llw[NP + p];
        float cst = 0.f;
#pragma unroll
        for (int r = 0; r < 4; ++r) {
            const int row = quad * 4 + r;
            const float x2r = __shfl(x2full, row, 64);   // lane 'row' holds row rb+row
            const float d = -2.f * facc[t * 4 + r] + x2r + p2p;
            out_dist[(size_t)(rb + row) * NP + p] = d;
            const float sim = log1pf((1.f - EPSV) / (d + EPSV));
            s0[r] += sim * w0;
            s1[r] += sim * w1;
            cst += sim;
        }
        cst += __shfl_xor(cst, 16, 64);
        cst += __shfl_xor(cst, 32, 64);
        if (quad == 0) atomicAdd(&gcol[p], cst);   // batch-wide column sum
    }

#pragma unroll
    for (int r = 0; r < 4; ++r) {
        float r0 = s0[r], r1 = s1[r];
#pragma unroll
        for (int m = 1; m <= 8; m <<= 1) {
            r0 += __shfl_xor(r0, m, 64);
            r1 += __shfl_xor(r1, m, 64);
        }
        if (lr == 0) {
            const int brow = rb + quad * 4 + r;
            out_logits[(size_t)brow * 2 + 0] = r0;
            out_logits[(size_t)brow * 2 + 1] = r1;
        }
    }
}

// -------------------------------------- jstar + pos[b] = V[jstar].sh[b]+bias
// grid 4096 x block 256 (4 waves, one row per wave). Thread 0 computes jstar
// from gcol (48 floats, L2-broadcast across blocks; first-max == argmax).
// Then identical to verified k_pos with vv = V[jstar].
__global__ __launch_bounds__(256) void k_pos(
    const float* __restrict__ sh,
    const float* __restrict__ V,         // [24][1024] candidate matvecs
    const float* __restrict__ gcol,      // [48] batch column sums
    const int*   __restrict__ flag,
    const float* __restrict__ bias,
    float* __restrict__ out_pos,
    float* __restrict__ out_copy)
{
    __shared__ int js;
    const int tid  = threadIdx.x;
    if (tid == 0) {
        const int idx = (flag[0] != 0) ? 1 : 0;
        const float* cs = gcol + idx * PPC;
        int bj = 0; float bv = cs[0];
        for (int j = 1; j < PPC; ++j)
            if (cs[j] > bv) { bv = cs[j]; bj = j; }   // first-max, like argmax
        js = bj;
    }
    __syncthreads();

    const int wave = tid >> 6;
    const int lane = tid & 63;
    const int b = blockIdx.x * 4 + wave;

    const floatx4* src = (const floatx4*)(sh + (size_t)b * HD);
    floatx4* dst = (floatx4*)(out_copy + (size_t)b * HD);
    const floatx4* vv = (const floatx4*)(V + (size_t)js * HD);
    float acc = 0.f;
#pragma unroll
    for (int c = 0; c < 4; ++c) {
        const int idx2 = c * 64 + lane;
        const floatx4 r = src[idx2];
        __builtin_nontemporal_store(r, &dst[idx2]);   // streaming copy, bit-exact
        const floatx4 vr = vv[idx2];
#pragma unroll
        for (int j = 0; j < 4; ++j) acc += r[j] * vr[j];
    }
#pragma unroll
    for (int m = 1; m <= 32; m <<= 1) acc += __shfl_xor(acc, m, 64);
    if (lane == 0) out_pos[b] = acc + bias[0];
}

extern "C" void kernel_launch(void* const* d_in, const int* in_sizes, int n_in,
                              void* d_out, int out_size, void* d_ws, size_t ws_size,
                              hipStream_t stream) {
    const float* x     = (const float*)d_in[0];  // specific_user [B,H] fp32
    const float* sh    = (const float*)d_in[1];  // shared_user   [B,H] fp32
    const float* proto = (const float*)d_in[2];  // [48,H] fp32
    const float* llw   = (const float*)d_in[3];  // [2,48] fp32
    const float* w2    = (const float*)d_in[4];  // [1,H,H] fp32
    const float* bb    = (const float*)d_in[5];  // [1] fp32
    const int*   flag  = (const int*)d_in[6];    // [1] int32

    float* out = (float*)d_out;
    // outputs flat: pos [B,1] | shared copy [B,H] | logits [B,2] | distance [B,48]
    float* out_pos    = out;
    float* out_copy   = out + BATCH;                           // 16384
    float* out_logits = out + BATCH + BATCH * HD;              // 16793600
    float* out_dist   = out + BATCH + BATCH * HD + BATCH * 2;  // 16826368

    // workspace layout (floats); total 74752 floats = 292 KB (ws proven
    // >= 6.7 MB in rounds 2-4):
    //   [0,48)          gcol  (zeroed in k_prep block 4; k_main atomics)
    //   [64,112)        p2
    //   [1024,25600)    V [24][1024]
    //   [25600,50176)   phi (48*1024 bf16-hi, as ushort)
    //   [50176,74752)   plo (48*1024 bf16-lo, as ushort)
    float* ws_col = (float*)d_ws;
    float* ws_p2  = ws_col + 64;
    float* ws_V   = ws_col + 1024;
    unsigned short* ws_phi = (unsigned short*)(ws_col + 25600);
    unsigned short* ws_plo = ws_phi + NP * HD;

    k_prep<<<144, 256, 0, stream>>>(proto, w2, flag, ws_phi, ws_plo, ws_p2, ws_col, ws_V);
    k_main<<<1024, 256, 0, stream>>>(x, ws_phi, ws_plo, llw, ws_p2, ws_col, out_logits, out_dist);
    k_pos<<<4096, 256, 0, stream>>>(sh, ws_V, ws_col, flag, bb, out_pos, out_copy);
}

// Round 7
// 233.717 us; speedup vs baseline: 1.8891x; 1.2092x over previous
//
#include <hip/hip_runtime.h>
#include <hip/hip_bf16.h>

// Problem constants (from reference)
#define BATCH 16384
#define HD    1024
#define NP    48
#define PPC   24
#define EPSV  1e-4f

typedef __attribute__((ext_vector_type(8))) short  short8;
typedef __attribute__((ext_vector_type(4))) float  floatx4;

__device__ __forceinline__ float b2f(unsigned short s) {
    union { unsigned u; float f; } c; c.u = ((unsigned)s) << 16; return c.f;
}
__device__ __forceinline__ unsigned short f2bu(float f) {
    __hip_bfloat16 h = __float2bfloat16(f);  // RNE
    union { __hip_bfloat16 h; unsigned short u; } c; c.h = h; return c.u;
}

// ---------------------------------------------------------------------------
// 3-dispatch structure (boundaries ~21us each; round-4 proved grid.sync ~90us):
//   k_prep : blocks 0-47   proto (hi,lo) bf16 split + p2 (+ zero gcol)
//            blocks 48-111 V-PARTIALS: Vp[ic][j][c] = sum_{i in chunk ic}
//                          proto[class,j][i] * W2[i][c] for all 24 candidates.
//                          Round-5 post-mortem: one-block-per-(j,c) serial
//                          1024-deep loop was 76us (latency chain, 4% occ).
//                          Now 64 blocks x 64-step loops, W2 read exactly
//                          once, proto slice in LDS (broadcast reads).
//   k_main : blocks 0-1023 verified GEMM+epilogue (52 VGPR, unroll 2 — the
//            proven no-spill configuration); blocks 1024-1047 reduce
//            Vp -> V[24][1024] (ordering to k_pos via kernel boundary).
//   k_pos  : jstar from gcol per-block, pos[b] = V[jstar].sh[b] + bias; copy.
// (Round-6 bench was an infra failure — container acquisition died twice,
//  no counters; this round resubmits the V-partial scheme with the
//  speculative kk-unroll-4 reverted to the proven unroll-2.)
// ---------------------------------------------------------------------------
__global__ __launch_bounds__(256) void k_prep(const float* __restrict__ proto,
                                              const float* __restrict__ w2,
                                              const int*   __restrict__ flag,
                                              unsigned short* __restrict__ phi,
                                              unsigned short* __restrict__ plo,
                                              float* __restrict__ p2,
                                              float* __restrict__ gcol,   // [48]
                                              float* __restrict__ Vp) {   // [16][24][1024]
    const int bid = blockIdx.x;
    const int tid = threadIdx.x;

    if (bid < 48) {
        // ---- proto -> (hi,lo) bf16 split + p2; block 4 zeroes gcol
        const int p = bid;
        if (p == 4 && tid < NP) gcol[tid] = 0.f;
        const float* row = proto + (size_t)p * HD;
        float acc = 0.f;
#pragma unroll
        for (int c = 0; c < 4; ++c) {
            const int k = c * 256 + tid;
            const float f = row[k];
            acc += f * f;
            const unsigned short h = f2bu(f);
            phi[(size_t)p * HD + k] = h;
            plo[(size_t)p * HD + k] = f2bu(f - b2f(h));
        }
#pragma unroll
        for (int m = 32; m >= 1; m >>= 1) acc += __shfl_xor(acc, m, 64);
        __shared__ float wsum[4];
        if ((tid & 63) == 0) wsum[tid >> 6] = acc;
        __syncthreads();
        if (tid == 0) p2[p] = wsum[0] + wsum[1] + wsum[2] + wsum[3];
    } else {
        // ---- V partials: block (ic, cc). 64-deep i loop, coalesced W2 reads,
        // proto slice broadcast from LDS, 24 accumulators in registers.
        __shared__ float pl[24][64];
        const int q  = bid - 48;          // [0,64)
        const int ic = q >> 2;            // 0..15 : i-chunk of 64 rows
        const int cc = q & 3;             // 0..3  : c-chunk of 256 cols
        const int i0 = ic * 64;
        const int c  = cc * 256 + tid;    // this thread's W2 column
        const int idx = (flag[0] != 0) ? 1 : 0;

        for (int t = tid; t < 24 * 64; t += 256) {
            const int j = t >> 6, i = t & 63;   // wave j-row, lane i: coalesced
            pl[j][i] = proto[(size_t)(idx * PPC + j) * HD + i0 + i];
        }
        __syncthreads();

        float acc[24];
#pragma unroll
        for (int j = 0; j < 24; ++j) acc[j] = 0.f;
#pragma unroll 4
        for (int i = 0; i < 64; ++i) {
            const float w = w2[(size_t)(i0 + i) * HD + c];
#pragma unroll
            for (int j = 0; j < 24; ++j) acc[j] += pl[j][i] * w;
        }
#pragma unroll
        for (int j = 0; j < 24; ++j)
            Vp[((size_t)ic * 24 + j) * HD + c] = acc[j];
    }
}

// ------------------------------------------------- main GEMM + epilogue
// blocks 0-1023: VERIFIED round-0 kernel, byte-identical inner loop
// (__launch_bounds__(256,4) -> 128-VGPR budget -> compiles to 52 VGPR, no
// spill; rounds 1/2 proved any 64-cap spills ~40MB scratch).
// blocks 1024-1047: reduce Vp -> V (tiny, runs concurrently).
// fp32 via split-bf16: x.p ~= xh.ph + xh.pl + xl.ph (3 MFMAs).
// MFMA 16x16x32 bf16: A[m=lane&15][k=quad*8+j], B[k=quad*8+j][n=lane&15],
// C/D col=lane&15, row=quad*4+reg.
__global__ __launch_bounds__(256, 4) void k_main(
    const float* __restrict__ x,
    const unsigned short* __restrict__ phi,
    const unsigned short* __restrict__ plo,
    const float* __restrict__ llw,       // [2,48] fp32
    const float* __restrict__ p2,
    const float* __restrict__ Vp,        // [16][24][1024] partials
    float* __restrict__ V,               // [24][1024] reduced
    float* __restrict__ gcol,            // [48] fp32, pre-zeroed (atomic)
    float* __restrict__ out_logits,      // [B,2]
    float* __restrict__ out_dist)        // [B,48]
{
    if (blockIdx.x >= 1024) {
        // ---- V reduce: one block per candidate prototype j
        const int j  = blockIdx.x - 1024;
        const int c4 = threadIdx.x * 4;
        floatx4 s = {0.f, 0.f, 0.f, 0.f};
#pragma unroll
        for (int ic = 0; ic < 16; ++ic) {
            const floatx4 v = *(const floatx4*)(Vp + ((size_t)ic * 24 + j) * HD + c4);
            s[0] += v[0]; s[1] += v[1]; s[2] += v[2]; s[3] += v[3];
        }
        *(floatx4*)(V + (size_t)j * HD + c4) = s;
        return;
    }

    __shared__ float lacc[4][64][13];    // 13: pad (12-stride = 8-way conflict)
    __shared__ float lx2[4][16];
    const int wave = threadIdx.x >> 6;
    const int lane = threadIdx.x & 63;
    const int quad = lane >> 4;
    const int lr   = lane & 15;
    const int rb   = blockIdx.x * 16;
    const int ko   = wave * 256;         // this wave's K-quarter

    const float* xr = x + (size_t)(rb + lr) * HD + ko + quad * 8;
    const unsigned short* ph0 = phi + (size_t)lr * HD + ko + quad * 8;
    const unsigned short* ph1 = ph0 + 16 * HD;
    const unsigned short* ph2 = ph0 + 32 * HD;
    const unsigned short* pl0 = plo + (size_t)lr * HD + ko + quad * 8;
    const unsigned short* pl1 = pl0 + 16 * HD;
    const unsigned short* pl2 = pl0 + 32 * HD;

    floatx4 acc0 = {0.f, 0.f, 0.f, 0.f};
    floatx4 acc1 = {0.f, 0.f, 0.f, 0.f};
    floatx4 acc2 = {0.f, 0.f, 0.f, 0.f};
    float x2p = 0.f;

#pragma unroll 2
    for (int kk = 0; kk < 8; ++kk) {
        const floatx4 xa = *(const floatx4*)(xr + kk * 32);
        const floatx4 xb = *(const floatx4*)(xr + kk * 32 + 4);
        short8 ah, al;
#pragma unroll
        for (int j = 0; j < 4; ++j) {
            const float f = xa[j];
            x2p += f * f;
            const unsigned short h = f2bu(f);
            ah[j] = (short)h;
            al[j] = (short)f2bu(f - b2f(h));
        }
#pragma unroll
        for (int j = 0; j < 4; ++j) {
            const float f = xb[j];
            x2p += f * f;
            const unsigned short h = f2bu(f);
            ah[4 + j] = (short)h;
            al[4 + j] = (short)f2bu(f - b2f(h));
        }
        const short8 bh0 = *(const short8*)(ph0 + kk * 32);
        const short8 bh1 = *(const short8*)(ph1 + kk * 32);
        const short8 bh2 = *(const short8*)(ph2 + kk * 32);
        const short8 bl0 = *(const short8*)(pl0 + kk * 32);
        const short8 bl1 = *(const short8*)(pl1 + kk * 32);
        const short8 bl2 = *(const short8*)(pl2 + kk * 32);
        acc0 = __builtin_amdgcn_mfma_f32_16x16x32_bf16(ah, bh0, acc0, 0, 0, 0);
        acc0 = __builtin_amdgcn_mfma_f32_16x16x32_bf16(ah, bl0, acc0, 0, 0, 0);
        acc0 = __builtin_amdgcn_mfma_f32_16x16x32_bf16(al, bh0, acc0, 0, 0, 0);
        acc1 = __builtin_amdgcn_mfma_f32_16x16x32_bf16(ah, bh1, acc1, 0, 0, 0);
        acc1 = __builtin_amdgcn_mfma_f32_16x16x32_bf16(ah, bl1, acc1, 0, 0, 0);
        acc1 = __builtin_amdgcn_mfma_f32_16x16x32_bf16(al, bh1, acc1, 0, 0, 0);
        acc2 = __builtin_amdgcn_mfma_f32_16x16x32_bf16(ah, bh2, acc2, 0, 0, 0);
        acc2 = __builtin_amdgcn_mfma_f32_16x16x32_bf16(ah, bl2, acc2, 0, 0, 0);
        acc2 = __builtin_amdgcn_mfma_f32_16x16x32_bf16(al, bh2, acc2, 0, 0, 0);
    }
    // per-wave: x2 partial for row lr over this wave's K-quarter
    x2p += __shfl_xor(x2p, 16, 64);
    x2p += __shfl_xor(x2p, 32, 64);

    // stash partial accumulators, combine on wave 0
#pragma unroll
    for (int r = 0; r < 4; ++r) {
        lacc[wave][lane][r]     = acc0[r];
        lacc[wave][lane][4 + r] = acc1[r];
        lacc[wave][lane][8 + r] = acc2[r];
    }
    if (quad == 0) lx2[wave][lr] = x2p;
    __syncthreads();
    if (wave != 0) return;

    float facc[12];
#pragma unroll
    for (int i = 0; i < 12; ++i)
        facc[i] = lacc[0][lane][i] + lacc[1][lane][i] + lacc[2][lane][i] + lacc[3][lane][i];
    const float x2full = lx2[0][lr] + lx2[1][lr] + lx2[2][lr] + lx2[3][lr]; // row lr

    float s0[4] = {0.f, 0.f, 0.f, 0.f};
    float s1[4] = {0.f, 0.f, 0.f, 0.f};

#pragma unroll
    for (int t = 0; t < 3; ++t) {
        const int p = t * 16 + lr;
        const float p2p = p2[p];
        const float w0 = llw[p];
        const float w1 = llw[NP + p];
        float cst = 0.f;
#pragma unroll
        for (int r = 0; r < 4; ++r) {
            const int row = quad * 4 + r;
            const float x2r = __shfl(x2full, row, 64);   // lane 'row' holds row rb+row
            const float d = -2.f * facc[t * 4 + r] + x2r + p2p;
            out_dist[(size_t)(rb + row) * NP + p] = d;
            const float sim = log1pf((1.f - EPSV) / (d + EPSV));
            s0[r] += sim * w0;
            s1[r] += sim * w1;
            cst += sim;
        }
        cst += __shfl_xor(cst, 16, 64);
        cst += __shfl_xor(cst, 32, 64);
        if (quad == 0) atomicAdd(&gcol[p], cst);   // batch-wide column sum
    }

#pragma unroll
    for (int r = 0; r < 4; ++r) {
        float r0 = s0[r], r1 = s1[r];
#pragma unroll
        for (int m = 1; m <= 8; m <<= 1) {
            r0 += __shfl_xor(r0, m, 64);
            r1 += __shfl_xor(r1, m, 64);
        }
        if (lr == 0) {
            const int brow = rb + quad * 4 + r;
            out_logits[(size_t)brow * 2 + 0] = r0;
            out_logits[(size_t)brow * 2 + 1] = r1;
        }
    }
}

// -------------------------------------- jstar + pos[b] = V[jstar].sh[b]+bias
// grid 4096 x block 256 (4 waves, one row per wave). Thread 0 computes jstar
// from gcol (48 floats, L2-broadcast; first-max == argmax).
__global__ __launch_bounds__(256) void k_pos(
    const float* __restrict__ sh,
    const float* __restrict__ V,         // [24][1024] candidate matvecs
    const float* __restrict__ gcol,      // [48] batch column sums
    const int*   __restrict__ flag,
    const float* __restrict__ bias,
    float* __restrict__ out_pos,
    float* __restrict__ out_copy)
{
    __shared__ int js;
    const int tid  = threadIdx.x;
    if (tid == 0) {
        const int idx = (flag[0] != 0) ? 1 : 0;
        const float* cs = gcol + idx * PPC;
        int bj = 0; float bv = cs[0];
        for (int j = 1; j < PPC; ++j)
            if (cs[j] > bv) { bv = cs[j]; bj = j; }   // first-max, like argmax
        js = bj;
    }
    __syncthreads();

    const int wave = tid >> 6;
    const int lane = tid & 63;
    const int b = blockIdx.x * 4 + wave;

    const floatx4* src = (const floatx4*)(sh + (size_t)b * HD);
    floatx4* dst = (floatx4*)(out_copy + (size_t)b * HD);
    const floatx4* vv = (const floatx4*)(V + (size_t)js * HD);
    float acc = 0.f;
#pragma unroll
    for (int c = 0; c < 4; ++c) {
        const int idx2 = c * 64 + lane;
        const floatx4 r = src[idx2];
        __builtin_nontemporal_store(r, &dst[idx2]);   // streaming copy, bit-exact
        const floatx4 vr = vv[idx2];
#pragma unroll
        for (int j = 0; j < 4; ++j) acc += r[j] * vr[j];
    }
#pragma unroll
    for (int m = 1; m <= 32; m <<= 1) acc += __shfl_xor(acc, m, 64);
    if (lane == 0) out_pos[b] = acc + bias[0];
}

extern "C" void kernel_launch(void* const* d_in, const int* in_sizes, int n_in,
                              void* d_out, int out_size, void* d_ws, size_t ws_size,
                              hipStream_t stream) {
    const float* x     = (const float*)d_in[0];  // specific_user [B,H] fp32
    const float* sh    = (const float*)d_in[1];  // shared_user   [B,H] fp32
    const float* proto = (const float*)d_in[2];  // [48,H] fp32
    const float* llw   = (const float*)d_in[3];  // [2,48] fp32
    const float* w2    = (const float*)d_in[4];  // [1,H,H] fp32
    const float* bb    = (const float*)d_in[5];  // [1] fp32
    const int*   flag  = (const int*)d_in[6];    // [1] int32

    float* out = (float*)d_out;
    // outputs flat: pos [B,1] | shared copy [B,H] | logits [B,2] | distance [B,48]
    float* out_pos    = out;
    float* out_copy   = out + BATCH;                           // 16384
    float* out_logits = out + BATCH + BATCH * HD;              // 16793600
    float* out_dist   = out + BATCH + BATCH * HD + BATCH * 2;  // 16826368

    // workspace layout (floats); total 467968 floats = 1.87 MB (ws proven
    // >= 6.7 MB: rounds 2-4 ran the big_ws path):
    //   [0,48)            gcol  (zeroed in k_prep block 4; k_main atomics)
    //   [64,112)          p2
    //   [1024,25600)      V  [24][1024]      (written by k_main reduce blocks)
    //   [25600,50176)     phi (48*1024 bf16-hi, as ushort)
    //   [50176,74752)     plo (48*1024 bf16-lo, as ushort)
    //   [74752,467968)    Vp [16][24][1024]  (written by k_prep V blocks)
    float* ws_col = (float*)d_ws;
    float* ws_p2  = ws_col + 64;
    float* ws_V   = ws_col + 1024;
    unsigned short* ws_phi = (unsigned short*)(ws_col + 25600);
    unsigned short* ws_plo = ws_phi + NP * HD;
    float* ws_Vp  = ws_col + 74752;

    k_prep<<<112, 256, 0, stream>>>(proto, w2, flag, ws_phi, ws_plo, ws_p2, ws_col, ws_Vp);
    k_main<<<1048, 256, 0, stream>>>(x, ws_phi, ws_plo, llw, ws_p2, ws_Vp, ws_V, ws_col, out_logits, out_dist);
    k_pos<<<4096, 256, 0, stream>>>(sh, ws_V, ws_col, flag, bb, out_pos, out_copy);
}

// Round 8
// 232.987 us; speedup vs baseline: 1.8950x; 1.0031x over previous
//
#include <hip/hip_runtime.h>
#include <hip/hip_bf16.h>

// Problem constants (from reference)
#define BATCH 16384
#define HD    1024
#define NP    48
#define PPC   24
#define EPSV  1e-4f

typedef __attribute__((ext_vector_type(8))) short  short8;
typedef __attribute__((ext_vector_type(4))) float  floatx4;

__device__ __forceinline__ float b2f(unsigned short s) {
    union { unsigned u; float f; } c; c.u = ((unsigned)s) << 16; return c.f;
}
__device__ __forceinline__ unsigned short f2bu(float f) {
    __hip_bfloat16 h = __float2bfloat16(f);  // RNE
    union { __hip_bfloat16 h; unsigned short u; } c; c.h = h; return c.u;
}

// ---------------------------------------------------------------------------
// Round-7 post-mortem: dur_us = ~157us fixed harness overhead + sum(kernels).
// (6-dispatch round-0 and 3-dispatch round-7 both ~76us kernel-sum -> both
// ~230 total; boundary count is irrelevant.) Only kernel time matters now.
//   k_pos  ~21us = HBM floor (128MB r+w / 6.3TB/s). Done.
//   k_prep ~8us. Minor.
//   k_main 47.5us @ 820GB/s, 25% occupancy -> latency-bound (too few loads
//          in flight). THIS round: 512-thread blocks, 8 waves, K-eighth per
//          wave -> 32 waves/CU. Round-1's 85us version of this shape failed
//          ONLY because __launch_bounds__(512,8) capped VGPR at 64 and the
//          loop spilled (VGPR 32, 54MB scratch). Plain __launch_bounds__(512)
//          leaves the allocator unconstrained: the proven loop body needs
//          ~52 VGPR, and 52 <= 64 means hardware grants 8 waves/SIMD anyway.
//          LDS 27KB x 4 blocks/CU = 108KB < 160KB.
// ---------------------------------------------------------------------------
__global__ __launch_bounds__(256) void k_prep(const float* __restrict__ proto,
                                              const float* __restrict__ w2,
                                              const int*   __restrict__ flag,
                                              unsigned short* __restrict__ phi,
                                              unsigned short* __restrict__ plo,
                                              float* __restrict__ p2,
                                              float* __restrict__ gcol,   // [48]
                                              float* __restrict__ Vp) {   // [16][24][1024]
    const int bid = blockIdx.x;
    const int tid = threadIdx.x;

    if (bid < 48) {
        // ---- proto -> (hi,lo) bf16 split + p2; block 4 zeroes gcol
        const int p = bid;
        if (p == 4 && tid < NP) gcol[tid] = 0.f;
        const float* row = proto + (size_t)p * HD;
        float acc = 0.f;
#pragma unroll
        for (int c = 0; c < 4; ++c) {
            const int k = c * 256 + tid;
            const float f = row[k];
            acc += f * f;
            const unsigned short h = f2bu(f);
            phi[(size_t)p * HD + k] = h;
            plo[(size_t)p * HD + k] = f2bu(f - b2f(h));
        }
#pragma unroll
        for (int m = 32; m >= 1; m >>= 1) acc += __shfl_xor(acc, m, 64);
        __shared__ float wsum[4];
        if ((tid & 63) == 0) wsum[tid >> 6] = acc;
        __syncthreads();
        if (tid == 0) p2[p] = wsum[0] + wsum[1] + wsum[2] + wsum[3];
    } else {
        // ---- V partials: block (ic, cc). 64-deep i loop, coalesced W2 reads,
        // proto slice broadcast from LDS, 24 accumulators in registers.
        __shared__ float pl[24][64];
        const int q  = bid - 48;          // [0,64)
        const int ic = q >> 2;            // 0..15 : i-chunk of 64 rows
        const int cc = q & 3;             // 0..3  : c-chunk of 256 cols
        const int i0 = ic * 64;
        const int c  = cc * 256 + tid;    // this thread's W2 column
        const int idx = (flag[0] != 0) ? 1 : 0;

        for (int t = tid; t < 24 * 64; t += 256) {
            const int j = t >> 6, i = t & 63;   // wave j-row, lane i: coalesced
            pl[j][i] = proto[(size_t)(idx * PPC + j) * HD + i0 + i];
        }
        __syncthreads();

        float acc[24];
#pragma unroll
        for (int j = 0; j < 24; ++j) acc[j] = 0.f;
#pragma unroll 4
        for (int i = 0; i < 64; ++i) {
            const float w = w2[(size_t)(i0 + i) * HD + c];
#pragma unroll
            for (int j = 0; j < 24; ++j) acc[j] += pl[j][i] * w;
        }
#pragma unroll
        for (int j = 0; j < 24; ++j)
            Vp[((size_t)ic * 24 + j) * HD + c] = acc[j];
    }
}

// ------------------------------------------------- main GEMM + epilogue
// blocks 0-1023: one 16-row band x 48 protos; 8 waves, each a K-EIGHTH (128).
// Inner-loop body is byte-identical to the verified 52-VGPR round-0 loop
// (just kk<4 instead of kk<8). NO min-waves launch-bounds arg: rounds 1/2
// proved any 64-VGPR cap spills ~40-50MB scratch. Hardware grants 8 waves/
// SIMD from actual usage (52<=64). blocks 1024-1047: reduce Vp -> V.
// fp32 via split-bf16: x.p ~= xh.ph + xh.pl + xl.ph (3 MFMAs).
// MFMA 16x16x32 bf16: A[m=lane&15][k=quad*8+j], B[k=quad*8+j][n=lane&15],
// C/D col=lane&15, row=quad*4+reg.
__global__ __launch_bounds__(512) void k_main(
    const float* __restrict__ x,
    const unsigned short* __restrict__ phi,
    const unsigned short* __restrict__ plo,
    const float* __restrict__ llw,       // [2,48] fp32
    const float* __restrict__ p2,
    const float* __restrict__ Vp,        // [16][24][1024] partials
    float* __restrict__ V,               // [24][1024] reduced
    float* __restrict__ gcol,            // [48] fp32, pre-zeroed (atomic)
    float* __restrict__ out_logits,      // [B,2]
    float* __restrict__ out_dist)        // [B,48]
{
    if (blockIdx.x >= 1024) {
        // ---- V reduce: one block per candidate prototype j (256 lanes used)
        if (threadIdx.x < 256) {
            const int j  = blockIdx.x - 1024;
            const int c4 = threadIdx.x * 4;
            floatx4 s = {0.f, 0.f, 0.f, 0.f};
#pragma unroll
            for (int ic = 0; ic < 16; ++ic) {
                const floatx4 v = *(const floatx4*)(Vp + ((size_t)ic * 24 + j) * HD + c4);
                s[0] += v[0]; s[1] += v[1]; s[2] += v[2]; s[3] += v[3];
            }
            *(floatx4*)(V + (size_t)j * HD + c4) = s;
        }
        return;
    }

    __shared__ float lacc[8][64][13];    // 13: pad (12-stride = 8-way conflict)
    __shared__ float lx2[8][16];
    const int wave = threadIdx.x >> 6;
    const int lane = threadIdx.x & 63;
    const int quad = lane >> 4;
    const int lr   = lane & 15;
    const int rb   = blockIdx.x * 16;
    const int ko   = wave * 128;         // this wave's K-eighth

    const float* xr = x + (size_t)(rb + lr) * HD + ko + quad * 8;
    const unsigned short* ph0 = phi + (size_t)lr * HD + ko + quad * 8;
    const unsigned short* ph1 = ph0 + 16 * HD;
    const unsigned short* ph2 = ph0 + 32 * HD;
    const unsigned short* pl0 = plo + (size_t)lr * HD + ko + quad * 8;
    const unsigned short* pl1 = pl0 + 16 * HD;
    const unsigned short* pl2 = pl0 + 32 * HD;

    floatx4 acc0 = {0.f, 0.f, 0.f, 0.f};
    floatx4 acc1 = {0.f, 0.f, 0.f, 0.f};
    floatx4 acc2 = {0.f, 0.f, 0.f, 0.f};
    float x2p = 0.f;

#pragma unroll 2
    for (int kk = 0; kk < 4; ++kk) {
        const floatx4 xa = *(const floatx4*)(xr + kk * 32);
        const floatx4 xb = *(const floatx4*)(xr + kk * 32 + 4);
        short8 ah, al;
#pragma unroll
        for (int j = 0; j < 4; ++j) {
            const float f = xa[j];
            x2p += f * f;
            const unsigned short h = f2bu(f);
            ah[j] = (short)h;
            al[j] = (short)f2bu(f - b2f(h));
        }
#pragma unroll
        for (int j = 0; j < 4; ++j) {
            const float f = xb[j];
            x2p += f * f;
            const unsigned short h = f2bu(f);
            ah[4 + j] = (short)h;
            al[4 + j] = (short)f2bu(f - b2f(h));
        }
        const short8 bh0 = *(const short8*)(ph0 + kk * 32);
        const short8 bh1 = *(const short8*)(ph1 + kk * 32);
        const short8 bh2 = *(const short8*)(ph2 + kk * 32);
        const short8 bl0 = *(const short8*)(pl0 + kk * 32);
        const short8 bl1 = *(const short8*)(pl1 + kk * 32);
        const short8 bl2 = *(const short8*)(pl2 + kk * 32);
        acc0 = __builtin_amdgcn_mfma_f32_16x16x32_bf16(ah, bh0, acc0, 0, 0, 0);
        acc0 = __builtin_amdgcn_mfma_f32_16x16x32_bf16(ah, bl0, acc0, 0, 0, 0);
        acc0 = __builtin_amdgcn_mfma_f32_16x16x32_bf16(al, bh0, acc0, 0, 0, 0);
        acc1 = __builtin_amdgcn_mfma_f32_16x16x32_bf16(ah, bh1, acc1, 0, 0, 0);
        acc1 = __builtin_amdgcn_mfma_f32_16x16x32_bf16(ah, bl1, acc1, 0, 0, 0);
        acc1 = __builtin_amdgcn_mfma_f32_16x16x32_bf16(al, bh1, acc1, 0, 0, 0);
        acc2 = __builtin_amdgcn_mfma_f32_16x16x32_bf16(ah, bh2, acc2, 0, 0, 0);
        acc2 = __builtin_amdgcn_mfma_f32_16x16x32_bf16(ah, bl2, acc2, 0, 0, 0);
        acc2 = __builtin_amdgcn_mfma_f32_16x16x32_bf16(al, bh2, acc2, 0, 0, 0);
    }
    // per-wave: x2 partial for row lr over this wave's K-eighth
    x2p += __shfl_xor(x2p, 16, 64);
    x2p += __shfl_xor(x2p, 32, 64);

    // stash partial accumulators, combine on wave 0
#pragma unroll
    for (int r = 0; r < 4; ++r) {
        lacc[wave][lane][r]     = acc0[r];
        lacc[wave][lane][4 + r] = acc1[r];
        lacc[wave][lane][8 + r] = acc2[r];
    }
    if (quad == 0) lx2[wave][lr] = x2p;
    __syncthreads();
    if (wave != 0) return;

    float facc[12];
#pragma unroll
    for (int i = 0; i < 12; ++i) {
        float s = 0.f;
#pragma unroll
        for (int w = 0; w < 8; ++w) s += lacc[w][lane][i];
        facc[i] = s;
    }
    float x2full = 0.f;
#pragma unroll
    for (int w = 0; w < 8; ++w) x2full += lx2[w][lr];   // row lr

    float s0[4] = {0.f, 0.f, 0.f, 0.f};
    float s1[4] = {0.f, 0.f, 0.f, 0.f};

#pragma unroll
    for (int t = 0; t < 3; ++t) {
        const int p = t * 16 + lr;
        const float p2p = p2[p];
        const float w0 = llw[p];
        const float w1 = llw[NP + p];
        float cst = 0.f;
#pragma unroll
        for (int r = 0; r < 4; ++r) {
            const int row = quad * 4 + r;
            const float x2r = __shfl(x2full, row, 64);   // lane 'row' holds row rb+row
            const float d = -2.f * facc[t * 4 + r] + x2r + p2p;
            out_dist[(size_t)(rb + row) * NP + p] = d;
            const float sim = log1pf((1.f - EPSV) / (d + EPSV));
            s0[r] += sim * w0;
            s1[r] += sim * w1;
            cst += sim;
        }
        cst += __shfl_xor(cst, 16, 64);
        cst += __shfl_xor(cst, 32, 64);
        if (quad == 0) atomicAdd(&gcol[p], cst);   // batch-wide column sum
    }

#pragma unroll
    for (int r = 0; r < 4; ++r) {
        float r0 = s0[r], r1 = s1[r];
#pragma unroll
        for (int m = 1; m <= 8; m <<= 1) {
            r0 += __shfl_xor(r0, m, 64);
            r1 += __shfl_xor(r1, m, 64);
        }
        if (lr == 0) {
            const int brow = rb + quad * 4 + r;
            out_logits[(size_t)brow * 2 + 0] = r0;
            out_logits[(size_t)brow * 2 + 1] = r1;
        }
    }
}

// -------------------------------------- jstar + pos[b] = V[jstar].sh[b]+bias
// grid 4096 x block 256 (4 waves, one row per wave). Thread 0 computes jstar
// from gcol (48 floats, L2-broadcast; first-max == argmax). At HBM floor.
__global__ __launch_bounds__(256) void k_pos(
    const float* __restrict__ sh,
    const float* __restrict__ V,         // [24][1024] candidate matvecs
    const float* __restrict__ gcol,      // [48] batch column sums
    const int*   __restrict__ flag,
    const float* __restrict__ bias,
    float* __restrict__ out_pos,
    float* __restrict__ out_copy)
{
    __shared__ int js;
    const int tid  = threadIdx.x;
    if (tid == 0) {
        const int idx = (flag[0] != 0) ? 1 : 0;
        const float* cs = gcol + idx * PPC;
        int bj = 0; float bv = cs[0];
        for (int j = 1; j < PPC; ++j)
            if (cs[j] > bv) { bv = cs[j]; bj = j; }   // first-max, like argmax
        js = bj;
    }
    __syncthreads();

    const int wave = tid >> 6;
    const int lane = tid & 63;
    const int b = blockIdx.x * 4 + wave;

    const floatx4* src = (const floatx4*)(sh + (size_t)b * HD);
    floatx4* dst = (floatx4*)(out_copy + (size_t)b * HD);
    const floatx4* vv = (const floatx4*)(V + (size_t)js * HD);
    float acc = 0.f;
#pragma unroll
    for (int c = 0; c < 4; ++c) {
        const int idx2 = c * 64 + lane;
        const floatx4 r = src[idx2];
        __builtin_nontemporal_store(r, &dst[idx2]);   // streaming copy, bit-exact
        const floatx4 vr = vv[idx2];
#pragma unroll
        for (int j = 0; j < 4; ++j) acc += r[j] * vr[j];
    }
#pragma unroll
    for (int m = 1; m <= 32; m <<= 1) acc += __shfl_xor(acc, m, 64);
    if (lane == 0) out_pos[b] = acc + bias[0];
}

extern "C" void kernel_launch(void* const* d_in, const int* in_sizes, int n_in,
                              void* d_out, int out_size, void* d_ws, size_t ws_size,
                              hipStream_t stream) {
    const float* x     = (const float*)d_in[0];  // specific_user [B,H] fp32
    const float* sh    = (const float*)d_in[1];  // shared_user   [B,H] fp32
    const float* proto = (const float*)d_in[2];  // [48,H] fp32
    const float* llw   = (const float*)d_in[3];  // [2,48] fp32
    const float* w2    = (const float*)d_in[4];  // [1,H,H] fp32
    const float* bb    = (const float*)d_in[5];  // [1] fp32
    const int*   flag  = (const int*)d_in[6];    // [1] int32

    float* out = (float*)d_out;
    // outputs flat: pos [B,1] | shared copy [B,H] | logits [B,2] | distance [B,48]
    float* out_pos    = out;
    float* out_copy   = out + BATCH;                           // 16384
    float* out_logits = out + BATCH + BATCH * HD;              // 16793600
    float* out_dist   = out + BATCH + BATCH * HD + BATCH * 2;  // 16826368

    // workspace layout (floats); total 467968 floats = 1.87 MB (ws proven
    // >= 6.7 MB: rounds 2-4 ran the big_ws path):
    //   [0,48)            gcol  (zeroed in k_prep block 4; k_main atomics)
    //   [64,112)          p2
    //   [1024,25600)      V  [24][1024]      (written by k_main reduce blocks)
    //   [25600,50176)     phi (48*1024 bf16-hi, as ushort)
    //   [50176,74752)     plo (48*1024 bf16-lo, as ushort)
    //   [74752,467968)    Vp [16][24][1024]  (written by k_prep V blocks)
    float* ws_col = (float*)d_ws;
    float* ws_p2  = ws_col + 64;
    float* ws_V   = ws_col + 1024;
    unsigned short* ws_phi = (unsigned short*)(ws_col + 25600);
    unsigned short* ws_plo = ws_phi + NP * HD;
    float* ws_Vp  = ws_col + 74752;

    k_prep<<<112, 256, 0, stream>>>(proto, w2, flag, ws_phi, ws_plo, ws_p2, ws_col, ws_Vp);
    k_main<<<1048, 512, 0, stream>>>(x, ws_phi, ws_plo, llw, ws_p2, ws_Vp, ws_V, ws_col, out_logits, out_dist);
    k_pos<<<4096, 256, 0, stream>>>(sh, ws_V, ws_col, flag, bb, out_pos, out_copy);
}